// Round 14
// baseline (115.147 us; speedup 1.0000x reference)
//
#include <hip/hip_runtime.h>

#define NTOK 4608   // token axis N = H*W/2
#define CCH  64     // feature axis C
#define HWSZ 9216   // H*W
#define NB   4      // batch
#define NSPL 8      // passA n-split
#define NCHT (NTOK/32)   // 144 chunks of 32 m
#define MSPL 8      // passB m-split
#define L2E  1.4426950408889634f

typedef unsigned short u16;
typedef __attribute__((ext_vector_type(4))) short s16x4;   // 4 bf16
typedef __attribute__((ext_vector_type(8))) short s16x8;   // 8 bf16
typedef __attribute__((ext_vector_type(4))) float f32x4;

__device__ __forceinline__ f32x4 mfma16(s16x8 a, s16x8 b, f32x4 c){
  return __builtin_amdgcn_mfma_f32_16x16x32_bf16(a, b, c, 0, 0, 0);
}
// HW bf16 convert (RNE; pairs fuse to v_cvt_pk_bf16_f32)
__device__ __forceinline__ short f2bfh(float f){
  __bf16 h = (__bf16)f;
  return (short)__builtin_bit_cast(unsigned short, h);
}
__device__ __forceinline__ float bf2f(u16 h){
  return __uint_as_float(((unsigned int)h) << 16);
}
// raw v_exp_f32 (2^x). Inputs bounded -> no fixup path needed.
__device__ __forceinline__ float ex2(float x){
  return __builtin_amdgcn_exp2f(x);
}

// global -> LDS direct copy, 16B per lane (dest = base + lane*16, linear).
__device__ __forceinline__ void gload16(const void* g, void* l){
  __builtin_amdgcn_global_load_lds(
      (const __attribute__((address_space(1))) void*)g,
      (__attribute__((address_space(3))) void*)l, 16, 0, 0);
}
#define SBAR() __builtin_amdgcn_sched_barrier(0)
#define WAITVM(N) do{ SBAR(); asm volatile("s_waitcnt vmcnt(" #N ")" ::: "memory"); SBAR(); }while(0)
#define PRIO(N) __builtin_amdgcn_s_setprio(N)

// ---------------------------------------------------------------------------
// Kernel 1: fused theta/phi/g projections. theta pre-scaled by log2(e).
// TH/PH[b][pos][c] bf16; G[b][c][m] bf16. Also zero-inits this block's
// OUTS slice (passB accumulates into it with fp32 atomics).
// ---------------------------------------------------------------------------
__global__ __launch_bounds__(512) void proj_kernel(
    const float* __restrict__ x, const float* __restrict__ y,
    const float* __restrict__ w_phi, const float* __restrict__ w_theta,
    const float* __restrict__ w_g,
    u16* __restrict__ TH, u16* __restrict__ PH, u16* __restrict__ G,
    float* __restrict__ OUTS){
  const int b = blockIdx.y;
  const int n = blockIdx.x*64 + (threadIdx.x & 63);
  const int wq = __builtin_amdgcn_readfirstlane((int)(threadIdx.x >> 6)); // 0..7
  // zero this block's OUTS slice (64 pos x 64 ch = 4096 f32; 8 f32/thread)
  {
    f32x4* zp = (f32x4*)(OUTS + ((size_t)b*NTOK + (size_t)blockIdx.x*64)*CCH);
    f32x4 z = {0.f,0.f,0.f,0.f};
    zp[threadIdx.x*2]   = z;
    zp[threadIdx.x*2+1] = z;
  }
  const float* xb = x + (size_t)b*CCH*HWSZ;
  const float* yb = y + (size_t)b*CCH*HWSZ;
  const float* wp = w_phi   + wq*4*CCH;
  const float* wt = w_theta + wq*4*CCH;
  const float* wg = w_g     + wq*4*CCH;
  float accP[8], accT[8], accG[8];
  #pragma unroll
  for(int j=0;j<8;++j){ accP[j]=0.f; accT[j]=0.f; accG[j]=0.f; }
  for(int k=0;k<CCH;k+=4){
    float xv0[4], xv1[4], yv0[4], yv1[4];
    #pragma unroll
    for(int u=0;u<4;++u){
      xv0[u] = xb[(size_t)(k+u)*HWSZ + n];
      xv1[u] = xb[(size_t)(k+u)*HWSZ + NTOK + n];
      yv0[u] = yb[(size_t)(k+u)*HWSZ + n];
      yv1[u] = yb[(size_t)(k+u)*HWSZ + NTOK + n];
    }
    #pragma unroll
    for(int u=0;u<4;++u)
      #pragma unroll
      for(int j=0;j<8;++j){
        float xv = (j&1)?xv1[u]:xv0[u];
        accP[j] = fmaf(wp[(j>>1)*CCH + k+u], xv, accP[j]);
        accT[j] = fmaf(wt[(j>>1)*CCH + k+u], (j&1)?yv1[u]:yv0[u], accT[j]);
        accG[j] = fmaf(wg[(j>>1)*CCH + k+u], xv, accG[j]);
      }
  }
  s16x8 vp, vt;
  #pragma unroll
  for(int j=0;j<8;++j){
    vp[j]=f2bfh(accP[j]);
    vt[j]=f2bfh(accT[j]*L2E);          // exp2-domain pre-scale
  }
  *(s16x8*)(PH + ((size_t)b*NTOK + n)*CCH + wq*8) = vp;
  *(s16x8*)(TH + ((size_t)b*NTOK + n)*CCH + wq*8) = vt;
  #pragma unroll
  for(int j=0;j<8;++j)
    G[((size_t)b*CCH + wq*8 + j)*NTOK + n] = f2bfh(accG[j]);
}

// ---------------------------------------------------------------------------
// Kernel 2: pass A — per-column sum of exp2(S'). 64-row TH chunks (8KB)
// staged via LDS ring (4 bufs), 2 gloads/wave/chunk, stage-ahead-2,
// counted vmcnt(4), XOR-swizzled b128 reads. (R10 configuration.)
// ---------------------------------------------------------------------------
__global__ __launch_bounds__(256, 4) void passA_kernel(
    const u16* __restrict__ TH, const u16* __restrict__ PH,
    float* __restrict__ CSUMP){
  __shared__ __align__(16) u16 ldsTH[4*4096];     // 4 bufs x 8KB
  const int bid = blockIdx.x;
  const int xcd = bid & 7, b = xcd >> 1;
  const int j = ((bid >> 3) << 1) | (xcd & 1);    // [0, 36*NSPL)
  const int part = j & (NSPL-1);
  const int mt = j >> 3;                           // NSPL == 8
  const int lane = threadIdx.x & 63;
  const int wq = __builtin_amdgcn_readfirstlane((int)(threadIdx.x >> 6));
  const int l15 = lane & 15, lg = lane >> 4;
  const int mbase = mt*128 + wq*32;
  const u16* thb = TH + (size_t)b*NTOK*CCH;
  const u16* phb = PH + (size_t)b*NTOK*CCH;
  const u16* p0 = phb + (size_t)(mbase + l15)*CCH + lg*8;
  const u16* p1 = p0 + 16*CCH;
  s16x8 bf00 = *(const s16x8*)p0, bf01 = *(const s16x8*)(p0+32);
  s16x8 bf10 = *(const s16x8*)p1, bf11 = *(const s16x8*)(p1+32);
  float rs0 = 0.f, rs1 = 0.f;

  const int NCH = (NTOK/NSPL)/64;                  // 9
  const int n0 = part*(NTOK/NSPL);
  // wave stages its 16-row block of the 64-row chunk, in two 8-row gloads.
  const int srl0 = wq*16 + (lane>>3);
  const int ssl0 = (lane&7) ^ (srl0&7);
  const int srl1 = srl0 + 8;
  const int ssl1 = (lane&7) ^ (srl1&7);
  auto STAGE = [&](int ci, int bi){
    const u16* base = thb + (size_t)(n0 + ci*64)*CCH;
    gload16(base + (size_t)srl0*CCH + ssl0*8, ldsTH + bi*4096 + wq*1024);
    gload16(base + (size_t)srl1*CCH + ssl1*8, ldsTH + bi*4096 + wq*1024 + 512);
  };

  STAGE(0, 0); SBAR();
  STAGE(1, 1); SBAR();
  #pragma unroll 1
  for(int t=0; t<NCH; ++t){
    int ci = t+2; if(ci >= NCH) ci -= NCH;         // dummy wrap (data unused)
    STAGE(ci, (t+2)&3);
    WAITVM(4);
    __builtin_amdgcn_s_barrier();
    const u16* bTH = ldsTH + (t&3)*4096;
    #pragma unroll
    for(int s=0;s<4;++s){
      const int r = s*16 + l15, rx = r & 7;
      const u16* rb = bTH + r*64;
      s16x8 a0 = *(const s16x8*)(rb + ((lg     ^ rx)<<3));
      s16x8 a1 = *(const s16x8*)(rb + (((lg+4) ^ rx)<<3));
      f32x4 v0 = {0.f,0.f,0.f,0.f}, v1 = {0.f,0.f,0.f,0.f};
      PRIO(1);
      v0 = mfma16(a0, bf00, v0); v0 = mfma16(a1, bf01, v0);
      v1 = mfma16(a0, bf10, v1); v1 = mfma16(a1, bf11, v1);
      PRIO(0);
      rs0 += (ex2(v0[0])+ex2(v0[1])) + (ex2(v0[2])+ex2(v0[3]));
      rs1 += (ex2(v1[0])+ex2(v1[1])) + (ex2(v1[2])+ex2(v1[3]));
    }
  }

  rs0 += __shfl_xor(rs0, 16); rs0 += __shfl_xor(rs0, 32);
  rs1 += __shfl_xor(rs1, 16); rs1 += __shfl_xor(rs1, 32);
  if(lg == 0){
    float* dst = CSUMP + (size_t)(part*NB + b)*NTOK + mbase;
    dst[l15]      = rs0;
    dst[16 + l15] = rs1;
  }
}

// ---------------------------------------------------------------------------
// Kernel 3: fused stat-merge + G scaling -> G2[b][ch][lg][c][8] PV B-frags.
// ---------------------------------------------------------------------------
__global__ __launch_bounds__(256) void scale_g_kernel(
    const u16* __restrict__ G, const float* __restrict__ CSUMP,
    u16* __restrict__ G2){
  __shared__ float dinv[32];
  const int tid = threadIdx.x;
  const int ch = blockIdx.x % NCHT;
  const int b  = blockIdx.x / NCHT;
  const int m0 = ch*32;
  if(tid < 32){
    float s = 0.f;
    #pragma unroll
    for(int h=0;h<NSPL;++h) s += CSUMP[(size_t)(h*NB+b)*NTOK + m0 + tid];
    dinv[tid] = 1.0f/s;
  }
  __syncthreads();
  const int c  = tid & 63;
  const int lg = tid >> 6;                    // 0..3
  const u16* gr = G + ((size_t)b*CCH + c)*NTOK + m0;
  s16x4 lo = *(const s16x4*)(gr + 4*lg);
  s16x4 hi = *(const s16x4*)(gr + 16 + 4*lg);
  s16x8 o;
  #pragma unroll
  for(int k=0;k<4;++k){
    o[k]   = f2bfh(bf2f((u16)lo[k]) * dinv[4*lg+k]);
    o[4+k] = f2bfh(bf2f((u16)hi[k]) * dinv[16+4*lg+k]);
  }
  *(s16x8*)(G2 + ((((size_t)b*NCHT + ch)*4 + lg)*CCH + c)*8) = o;
}

// ---------------------------------------------------------------------------
// Kernel 4: pass B — PH staged via LDS ring (ahead-2, vmcnt counted);
// G2 fragments register-loaded per chunk; P = exp2(S'); PV into fp32 acc;
// epilogue accumulates into fp32 OUTS with global atomics (no partial
// buffers, no reduce kernel).
// ---------------------------------------------------------------------------
__global__ __launch_bounds__(256, 4) void passB_kernel(
    const u16* __restrict__ TH, const u16* __restrict__ PH,
    const u16* __restrict__ G2, float* __restrict__ OUTS){
  __shared__ __align__(16) u16 ldsPH[4*2048];
  const int bid = blockIdx.x;
  const int xcd = bid & 7, b = xcd >> 1;
  const int j = ((bid >> 3) << 1) | (xcd & 1);    // [0, 36*MSPL)
  const int mpart = j % MSPL;
  const int nt = j / MSPL;                         // [0, 36)
  const int lane = threadIdx.x & 63;
  const int wq = __builtin_amdgcn_readfirstlane((int)(threadIdx.x >> 6));
  const int l15 = lane & 15, lg = lane >> 4;
  const int nbase = nt*128 + wq*32;
  const u16* thb = TH + (size_t)b*NTOK*CCH;
  const u16* phb = PH + (size_t)b*NTOK*CCH;
  const u16* g2b = G2 + (size_t)b*NCHT*4*CCH*8;
  const u16* t0 = thb + (size_t)(nbase + l15)*CCH + lg*8;
  const u16* t1 = t0 + 16*CCH;
  s16x8 bt00 = *(const s16x8*)t0, bt01 = *(const s16x8*)(t0+32);
  s16x8 bt10 = *(const s16x8*)t1, bt11 = *(const s16x8*)(t1+32);
  f32x4 acc[2][4];
  #pragma unroll
  for(int n2=0;n2<2;++n2)
    #pragma unroll
    for(int ct=0;ct<4;++ct) acc[n2][ct] = (f32x4){0.f,0.f,0.f,0.f};

  const int mcnt = NTOK/MSPL;
  const int NCH = mcnt/32;                         // 18
  const int ch0 = (mpart*mcnt)/32;

  const int srl = wq*8 + (lane>>3);
  const int ssl = (lane&7) ^ (srl&7);
  auto STAGE_PH = [&](int ci, int bi){
    gload16(phb + (size_t)((ch0+ci)*32 + srl)*CCH + ssl*8,
            ldsPH + bi*2048 + wq*512);
  };

  STAGE_PH(0, 0); SBAR();
  STAGE_PH(1, 1); SBAR();
  #pragma unroll 1
  for(int t=0; t<NCH; ++t){
    WAITVM(1);
    __builtin_amdgcn_s_barrier();
    // G2 register loads for chunk t (4 x b128, 4x256B dense per wave)
    const u16* gp = g2b + ((size_t)((ch0+t)*4 + lg)*CCH + l15)*8;
    s16x8 g0 = *(const s16x8*)(gp);
    s16x8 g1 = *(const s16x8*)(gp + 128);
    s16x8 g2 = *(const s16x8*)(gp + 256);
    s16x8 g3 = *(const s16x8*)(gp + 384);
    SBAR();                                        // pin G before STAGE
    int c2 = t+2; if(c2 >= NCH) c2 -= NCH;
    STAGE_PH(c2, (t+2)&3);
    SBAR();                                        // pin staging before compute
    // A-frags from LDS (XOR-unswizzled b128)
    const u16* bPH = ldsPH + (t&3)*2048;
    const int rx = l15 & 7;
    const u16* rb0 = bPH + l15*64;
    const u16* rb1 = rb0 + 16*64;
    s16x8 ap00 = *(const s16x8*)(rb0 + ((lg     ^ rx)<<3));
    s16x8 ap01 = *(const s16x8*)(rb0 + (((lg+4) ^ rx)<<3));
    s16x8 ap10 = *(const s16x8*)(rb1 + ((lg     ^ rx)<<3));
    s16x8 ap11 = *(const s16x8*)(rb1 + (((lg+4) ^ rx)<<3));
    // S' (transposed): lane holds S[n=l15][m = ms*16 + 4*lg + r]
    f32x4 s00={0.f,0.f,0.f,0.f}, s01={0.f,0.f,0.f,0.f};
    f32x4 s10={0.f,0.f,0.f,0.f}, s11={0.f,0.f,0.f,0.f};
    PRIO(1);
    s00 = mfma16(ap00, bt00, s00); s00 = mfma16(ap01, bt01, s00);
    s01 = mfma16(ap10, bt00, s01); s01 = mfma16(ap11, bt01, s01);
    s10 = mfma16(ap00, bt10, s10); s10 = mfma16(ap01, bt11, s10);
    s11 = mfma16(ap10, bt10, s11); s11 = mfma16(ap11, bt11, s11);
    PRIO(0);
    // P = exp2(S') via raw v_exp_f32, packed to bf16 (cvt_pk)
    s16x8 pa0, pa1;
    #pragma unroll
    for(int r=0;r<4;++r){
      pa0[r]   = f2bfh(ex2(s00[r]));
      pa0[4+r] = f2bfh(ex2(s01[r]));
      pa1[r]   = f2bfh(ex2(s10[r]));
      pa1[4+r] = f2bfh(ex2(s11[r]));
    }
    // PV (auto-wait here is counted: keeps PH(t+2) in flight)
    PRIO(1);
    acc[0][0] = mfma16(pa0, g0, acc[0][0]);
    acc[1][0] = mfma16(pa1, g0, acc[1][0]);
    acc[0][1] = mfma16(pa0, g1, acc[0][1]);
    acc[1][1] = mfma16(pa1, g1, acc[1][1]);
    acc[0][2] = mfma16(pa0, g2, acc[0][2]);
    acc[1][2] = mfma16(pa1, g2, acc[1][2]);
    acc[0][3] = mfma16(pa0, g3, acc[0][3]);
    acc[1][3] = mfma16(pa1, g3, acc[1][3]);
    PRIO(0);
  }

  float* outp = OUTS + ((size_t)b*NTOK)*CCH;
  #pragma unroll
  for(int n2=0;n2<2;++n2)
    #pragma unroll
    for(int ct=0;ct<4;++ct)
      #pragma unroll
      for(int r=0;r<4;++r)
        atomicAdd(&outp[(size_t)(nbase + n2*16 + lg*4 + r)*CCH + ct*16 + l15],
                  acc[n2][ct][r]);
}

// ---------------------------------------------------------------------------
// Kernel 5: w_mask 1x1 conv + residual. 512 thr = 64 tokens x 8 waves
// (8 output channels each); OUTS read as fp32 f32x4.
// ---------------------------------------------------------------------------
__global__ __launch_bounds__(512, 2) void conv_kernel(
    const float* __restrict__ OUTS, const float* __restrict__ w_mask,
    const float* __restrict__ x, float* __restrict__ out){
  const int b = blockIdx.y;
  const int nl = threadIdx.x & 63;
  const int n = blockIdx.x*64 + nl;
  const int q = __builtin_amdgcn_readfirstlane((int)(threadIdx.x >> 6)); // 0..7
  const f32x4* vr = (const f32x4*)(OUTS + ((size_t)b*NTOK + n)*CCH);
  float v[64];
  #pragma unroll
  for(int k=0;k<16;++k){
    f32x4 u = vr[k];
    v[4*k]=u[0]; v[4*k+1]=u[1]; v[4*k+2]=u[2]; v[4*k+3]=u[3];
  }
  const float* wm = w_mask + q*8*32;       // 8 rows of 32, wave-uniform
  #pragma unroll
  for(int jj=0;jj<8;++jj){
    float a0 = 0.f, a1 = 0.f;
    #pragma unroll
    for(int ic=0;ic<32;++ic){
      float w = wm[jj*32 + ic];
      a0 = fmaf(w, v[2*ic],   a0);
      a1 = fmaf(w, v[2*ic+1], a1);
    }
    const size_t idx = ((size_t)b*CCH + q*8 + jj)*HWSZ + n;
    out[idx]        = a0 + x[idx];
    out[idx + NTOK] = a1 + x[idx + NTOK];
  }
}

// ---------------------------------------------------------------------------
extern "C" void kernel_launch(void* const* d_in, const int* in_sizes, int n_in,
                              void* d_out, int out_size, void* d_ws, size_t ws_size,
                              hipStream_t stream){
  const float* x       = (const float*)d_in[0];
  const float* y       = (const float*)d_in[1];
  const float* w_phi   = (const float*)d_in[2];
  const float* w_theta = (const float*)d_in[3];
  const float* w_g     = (const float*)d_in[4];
  const float* w_mask  = (const float*)d_in[5];
  float* out = (float*)d_out;
  char* ws = (char*)d_ws;

  const size_t projB  = (size_t)NB*NTOK*CCH*sizeof(u16);    // 2,359,296
  const size_t outsB  = (size_t)NB*NTOK*CCH*sizeof(float);  // 4,718,592
  const size_t fstat  = (size_t)NB*NTOK*sizeof(float);      // 73,728

  size_t off = 0;
  u16*   TH    = (u16*)(ws + off); off += projB;
  u16*   PH    = (u16*)(ws + off); off += projB;
  u16*   G     = (u16*)(ws + off); off += projB;
  u16*   G2    = (u16*)(ws + off); off += projB;
  float* OUTS  = (float*)(ws + off); off += outsB;
  float* CSUMP = (float*)(ws + off); off += (size_t)NSPL*fstat;

  proj_kernel<<<dim3(NTOK/64, NB), 512, 0, stream>>>(x, y, w_phi, w_theta, w_g,
                                                     TH, PH, G, OUTS);
  passA_kernel<<<dim3((NTOK/128)*NSPL*NB), 256, 0, stream>>>(TH, PH, CSUMP);
  scale_g_kernel<<<dim3(NB*NCHT), 256, 0, stream>>>(G, CSUMP, G2);
  passB_kernel<<<dim3((NTOK/128)*MSPL*NB), 256, 0, stream>>>(TH, PH, G2, OUTS);
  conv_kernel<<<dim3(NTOK/64, NB), 512, 0, stream>>>(OUTS, w_mask, x, out);
}

// Round 15
// 97.513 us; speedup vs baseline: 1.1808x; 1.1808x over previous
//
#include <hip/hip_runtime.h>

#define NTOK 4608   // token axis N = H*W/2
#define CCH  64     // feature axis C
#define HWSZ 9216   // H*W
#define NB   4      // batch
#define NSPL 8      // passA n-split
#define NCHT (NTOK/32)   // 144 chunks of 32 m
#define L2E  1.4426950408889634f

typedef unsigned short u16;
typedef __attribute__((ext_vector_type(4))) short s16x4;   // 4 bf16
typedef __attribute__((ext_vector_type(8))) short s16x8;   // 8 bf16
typedef __attribute__((ext_vector_type(4))) float f32x4;

__device__ __forceinline__ f32x4 mfma16(s16x8 a, s16x8 b, f32x4 c){
  return __builtin_amdgcn_mfma_f32_16x16x32_bf16(a, b, c, 0, 0, 0);
}
// HW bf16 convert (RNE; pairs fuse to v_cvt_pk_bf16_f32)
__device__ __forceinline__ short f2bfh(float f){
  __bf16 h = (__bf16)f;
  return (short)__builtin_bit_cast(unsigned short, h);
}
__device__ __forceinline__ float bf2f(u16 h){
  return __uint_as_float(((unsigned int)h) << 16);
}
// raw v_exp_f32 (2^x). Inputs bounded -> no fixup path needed.
__device__ __forceinline__ float ex2(float x){
  return __builtin_amdgcn_exp2f(x);
}

// global -> LDS direct copy, 16B per lane (dest = base + lane*16, linear).
__device__ __forceinline__ void gload16(const void* g, void* l){
  __builtin_amdgcn_global_load_lds(
      (const __attribute__((address_space(1))) void*)g,
      (__attribute__((address_space(3))) void*)l, 16, 0, 0);
}
#define SBAR() __builtin_amdgcn_sched_barrier(0)
#define WAITVM(N) do{ SBAR(); asm volatile("s_waitcnt vmcnt(" #N ")" ::: "memory"); SBAR(); }while(0)
#define PRIO(N) __builtin_amdgcn_s_setprio(N)

// ---------------------------------------------------------------------------
// Kernel 1: fused theta/phi/g projections. theta pre-scaled by log2(e).
// TH/PH[b][pos][c] bf16; G[b][c][m] bf16.
// ---------------------------------------------------------------------------
__global__ __launch_bounds__(512) void proj_kernel(
    const float* __restrict__ x, const float* __restrict__ y,
    const float* __restrict__ w_phi, const float* __restrict__ w_theta,
    const float* __restrict__ w_g,
    u16* __restrict__ TH, u16* __restrict__ PH, u16* __restrict__ G){
  const int b = blockIdx.y;
  const int n = blockIdx.x*64 + (threadIdx.x & 63);
  const int wq = __builtin_amdgcn_readfirstlane((int)(threadIdx.x >> 6)); // 0..7
  const float* xb = x + (size_t)b*CCH*HWSZ;
  const float* yb = y + (size_t)b*CCH*HWSZ;
  const float* wp = w_phi   + wq*4*CCH;
  const float* wt = w_theta + wq*4*CCH;
  const float* wg = w_g     + wq*4*CCH;
  float accP[8], accT[8], accG[8];
  #pragma unroll
  for(int j=0;j<8;++j){ accP[j]=0.f; accT[j]=0.f; accG[j]=0.f; }
  for(int k=0;k<CCH;k+=4){
    float xv0[4], xv1[4], yv0[4], yv1[4];
    #pragma unroll
    for(int u=0;u<4;++u){
      xv0[u] = xb[(size_t)(k+u)*HWSZ + n];
      xv1[u] = xb[(size_t)(k+u)*HWSZ + NTOK + n];
      yv0[u] = yb[(size_t)(k+u)*HWSZ + n];
      yv1[u] = yb[(size_t)(k+u)*HWSZ + NTOK + n];
    }
    #pragma unroll
    for(int u=0;u<4;++u)
      #pragma unroll
      for(int j=0;j<8;++j){
        float xv = (j&1)?xv1[u]:xv0[u];
        accP[j] = fmaf(wp[(j>>1)*CCH + k+u], xv, accP[j]);
        accT[j] = fmaf(wt[(j>>1)*CCH + k+u], (j&1)?yv1[u]:yv0[u], accT[j]);
        accG[j] = fmaf(wg[(j>>1)*CCH + k+u], xv, accG[j]);
      }
  }
  s16x8 vp, vt;
  #pragma unroll
  for(int j=0;j<8;++j){
    vp[j]=f2bfh(accP[j]);
    vt[j]=f2bfh(accT[j]*L2E);          // exp2-domain pre-scale
  }
  *(s16x8*)(PH + ((size_t)b*NTOK + n)*CCH + wq*8) = vp;
  *(s16x8*)(TH + ((size_t)b*NTOK + n)*CCH + wq*8) = vt;
  #pragma unroll
  for(int j=0;j<8;++j)
    G[((size_t)b*CCH + wq*8 + j)*NTOK + n] = f2bfh(accG[j]);
}

// ---------------------------------------------------------------------------
// Kernel 2: pass A — per-column sum of exp2(S'). 64-row TH chunks (8KB)
// staged via LDS ring (4 bufs), 2 gloads/wave/chunk, stage-ahead-2,
// counted vmcnt(4), XOR-swizzled b128 reads. (R10 configuration.)
// ---------------------------------------------------------------------------
__global__ __launch_bounds__(256, 4) void passA_kernel(
    const u16* __restrict__ TH, const u16* __restrict__ PH,
    float* __restrict__ CSUMP){
  __shared__ __align__(16) u16 ldsTH[4*4096];     // 4 bufs x 8KB
  const int bid = blockIdx.x;
  const int xcd = bid & 7, b = xcd >> 1;
  const int j = ((bid >> 3) << 1) | (xcd & 1);    // [0, 36*NSPL)
  const int part = j & (NSPL-1);
  const int mt = j >> 3;                           // NSPL == 8
  const int lane = threadIdx.x & 63;
  const int wq = __builtin_amdgcn_readfirstlane((int)(threadIdx.x >> 6));
  const int l15 = lane & 15, lg = lane >> 4;
  const int mbase = mt*128 + wq*32;
  const u16* thb = TH + (size_t)b*NTOK*CCH;
  const u16* phb = PH + (size_t)b*NTOK*CCH;
  const u16* p0 = phb + (size_t)(mbase + l15)*CCH + lg*8;
  const u16* p1 = p0 + 16*CCH;
  s16x8 bf00 = *(const s16x8*)p0, bf01 = *(const s16x8*)(p0+32);
  s16x8 bf10 = *(const s16x8*)p1, bf11 = *(const s16x8*)(p1+32);
  float rs0 = 0.f, rs1 = 0.f;

  const int NCH = (NTOK/NSPL)/64;                  // 9
  const int n0 = part*(NTOK/NSPL);
  // wave stages its 16-row block of the 64-row chunk, in two 8-row gloads.
  const int srl0 = wq*16 + (lane>>3);
  const int ssl0 = (lane&7) ^ (srl0&7);
  const int srl1 = srl0 + 8;
  const int ssl1 = (lane&7) ^ (srl1&7);
  auto STAGE = [&](int ci, int bi){
    const u16* base = thb + (size_t)(n0 + ci*64)*CCH;
    gload16(base + (size_t)srl0*CCH + ssl0*8, ldsTH + bi*4096 + wq*1024);
    gload16(base + (size_t)srl1*CCH + ssl1*8, ldsTH + bi*4096 + wq*1024 + 512);
  };

  STAGE(0, 0); SBAR();
  STAGE(1, 1); SBAR();
  #pragma unroll 1
  for(int t=0; t<NCH; ++t){
    int ci = t+2; if(ci >= NCH) ci -= NCH;         // dummy wrap (data unused)
    STAGE(ci, (t+2)&3);
    WAITVM(4);
    __builtin_amdgcn_s_barrier();
    const u16* bTH = ldsTH + (t&3)*4096;
    #pragma unroll
    for(int s=0;s<4;++s){
      const int r = s*16 + l15, rx = r & 7;
      const u16* rb = bTH + r*64;
      s16x8 a0 = *(const s16x8*)(rb + ((lg     ^ rx)<<3));
      s16x8 a1 = *(const s16x8*)(rb + (((lg+4) ^ rx)<<3));
      f32x4 v0 = {0.f,0.f,0.f,0.f}, v1 = {0.f,0.f,0.f,0.f};
      PRIO(1);
      v0 = mfma16(a0, bf00, v0); v0 = mfma16(a1, bf01, v0);
      v1 = mfma16(a0, bf10, v1); v1 = mfma16(a1, bf11, v1);
      PRIO(0);
      rs0 += (ex2(v0[0])+ex2(v0[1])) + (ex2(v0[2])+ex2(v0[3]));
      rs1 += (ex2(v1[0])+ex2(v1[1])) + (ex2(v1[2])+ex2(v1[3]));
    }
  }

  rs0 += __shfl_xor(rs0, 16); rs0 += __shfl_xor(rs0, 32);
  rs1 += __shfl_xor(rs1, 16); rs1 += __shfl_xor(rs1, 32);
  if(lg == 0){
    float* dst = CSUMP + (size_t)(part*NB + b)*NTOK + mbase;
    dst[l15]      = rs0;
    dst[16 + l15] = rs1;
  }
}

// ---------------------------------------------------------------------------
// Kernel 3: fused stat-merge + G scaling -> G2[b][ch][lg][c][8] PV B-frags.
// ---------------------------------------------------------------------------
__global__ __launch_bounds__(256) void scale_g_kernel(
    const u16* __restrict__ G, const float* __restrict__ CSUMP,
    u16* __restrict__ G2){
  __shared__ float dinv[32];
  const int tid = threadIdx.x;
  const int ch = blockIdx.x % NCHT;
  const int b  = blockIdx.x / NCHT;
  const int m0 = ch*32;
  if(tid < 32){
    float s = 0.f;
    #pragma unroll
    for(int h=0;h<NSPL;++h) s += CSUMP[(size_t)(h*NB+b)*NTOK + m0 + tid];
    dinv[tid] = 1.0f/s;
  }
  __syncthreads();
  const int c  = tid & 63;
  const int lg = tid >> 6;                    // 0..3
  const u16* gr = G + ((size_t)b*CCH + c)*NTOK + m0;
  s16x4 lo = *(const s16x4*)(gr + 4*lg);
  s16x4 hi = *(const s16x4*)(gr + 16 + 4*lg);
  s16x8 o;
  #pragma unroll
  for(int k=0;k<4;++k){
    o[k]   = f2bfh(bf2f((u16)lo[k]) * dinv[4*lg+k]);
    o[4+k] = f2bfh(bf2f((u16)hi[k]) * dinv[16+4*lg+k]);
  }
  *(s16x8*)(G2 + ((((size_t)b*NCHT + ch)*4 + lg)*CCH + c)*8) = o;
}

// ---------------------------------------------------------------------------
// Kernel 4: pass B — 64-m chunks (halved barrier count vs R10): PH staged
// via LDS ring (4 bufs x 8KB, 2 gloads/wave/chunk, stage-ahead-2, counted
// WAITVM(2)); 8 G2 fragment loads per iter issued before the barrier and
// pinned before STAGE (PV auto-wait stays counted); two statically-unrolled
// 32-m compute halves per iter; bf16 partial store.
// ---------------------------------------------------------------------------
template<int MSPLIT>
__global__ __launch_bounds__(256, 4) void passB_kernel(
    const u16* __restrict__ TH, const u16* __restrict__ PH,
    const u16* __restrict__ G2, u16* __restrict__ OUTPB){
  __shared__ __align__(16) u16 ldsPH[4*4096];      // 4 bufs x 8KB (64 m-rows)
  const int bid = blockIdx.x;
  const int xcd = bid & 7, b = xcd >> 1;
  const int j = ((bid >> 3) << 1) | (xcd & 1);     // [0, 36*MSPLIT)
  const int mpart = j % MSPLIT;
  const int nt = j / MSPLIT;                        // [0, 36)
  const int lane = threadIdx.x & 63;
  const int wq = __builtin_amdgcn_readfirstlane((int)(threadIdx.x >> 6));
  const int l15 = lane & 15, lg = lane >> 4;
  const int nbase = nt*128 + wq*32;
  const u16* thb = TH + (size_t)b*NTOK*CCH;
  const u16* phb = PH + (size_t)b*NTOK*CCH;
  const u16* g2b = G2 + (size_t)b*NCHT*4*CCH*8;
  const u16* t0 = thb + (size_t)(nbase + l15)*CCH + lg*8;
  const u16* t1 = t0 + 16*CCH;
  s16x8 bt00 = *(const s16x8*)t0, bt01 = *(const s16x8*)(t0+32);
  s16x8 bt10 = *(const s16x8*)t1, bt11 = *(const s16x8*)(t1+32);
  f32x4 acc[2][4];
  #pragma unroll
  for(int n2=0;n2<2;++n2)
    #pragma unroll
    for(int ct=0;ct<4;++ct) acc[n2][ct] = (f32x4){0.f,0.f,0.f,0.f};

  const int mcnt = NTOK/MSPLIT;
  const int NCH = mcnt/64;                          // 9 at MSPLIT=8
  const int ch0 = (mpart*mcnt)/32;                  // base 32-chunk for G2
  const int m0 = mpart*mcnt;

  // wave stages its 16-row block of the 64-row chunk, in two 8-row gloads.
  const int srl0 = wq*16 + (lane>>3);
  const int ssl0 = (lane&7) ^ (srl0&7);
  const int srl1 = srl0 + 8;
  const int ssl1 = (lane&7) ^ (srl1&7);
  auto STAGE_PH = [&](int ci, int bi){
    const u16* base = phb + (size_t)(m0 + ci*64)*CCH;
    gload16(base + (size_t)srl0*CCH + ssl0*8, ldsPH + bi*4096 + wq*1024);
    gload16(base + (size_t)srl1*CCH + ssl1*8, ldsPH + bi*4096 + wq*1024 + 512);
  };

  STAGE_PH(0, 0); SBAR();
  STAGE_PH(1, 1); SBAR();
  #pragma unroll 1
  for(int t=0; t<NCH; ++t){
    WAITVM(2);
    // G2 register loads for BOTH 32-chunks of this iter (8 x b128);
    // issued before the barrier for extra latency headroom.
    const u16* gp0 = g2b + ((size_t)((ch0 + 2*t)*4 + lg)*CCH + l15)*8;
    const u16* gp1 = gp0 + (size_t)4*CCH*8;
    s16x8 g0 = *(const s16x8*)(gp0);
    s16x8 g1 = *(const s16x8*)(gp0 + 128);
    s16x8 g2 = *(const s16x8*)(gp0 + 256);
    s16x8 g3 = *(const s16x8*)(gp0 + 384);
    s16x8 g4 = *(const s16x8*)(gp1);
    s16x8 g5 = *(const s16x8*)(gp1 + 128);
    s16x8 g6 = *(const s16x8*)(gp1 + 256);
    s16x8 g7 = *(const s16x8*)(gp1 + 384);
    SBAR();
    __builtin_amdgcn_s_barrier();
    int c2 = t+2; if(c2 >= NCH) c2 -= NCH;
    STAGE_PH(c2, (t+2)&3);
    SBAR();                                         // pin staging before compute
    const u16* bPH = ldsPH + (t&3)*4096;
    const int rx = l15 & 7;

    // ---- sub-chunk 0 (m rows 0..31 of this 64-chunk) ----
    {
      const u16* rb0 = bPH + l15*64;
      const u16* rb1 = rb0 + 16*64;
      s16x8 ap00 = *(const s16x8*)(rb0 + ((lg     ^ rx)<<3));
      s16x8 ap01 = *(const s16x8*)(rb0 + (((lg+4) ^ rx)<<3));
      s16x8 ap10 = *(const s16x8*)(rb1 + ((lg     ^ rx)<<3));
      s16x8 ap11 = *(const s16x8*)(rb1 + (((lg+4) ^ rx)<<3));
      f32x4 s00={0.f,0.f,0.f,0.f}, s01={0.f,0.f,0.f,0.f};
      f32x4 s10={0.f,0.f,0.f,0.f}, s11={0.f,0.f,0.f,0.f};
      PRIO(1);
      s00 = mfma16(ap00, bt00, s00); s00 = mfma16(ap01, bt01, s00);
      s01 = mfma16(ap10, bt00, s01); s01 = mfma16(ap11, bt01, s01);
      s10 = mfma16(ap00, bt10, s10); s10 = mfma16(ap01, bt11, s10);
      s11 = mfma16(ap10, bt10, s11); s11 = mfma16(ap11, bt11, s11);
      PRIO(0);
      s16x8 pa0, pa1;
      #pragma unroll
      for(int r=0;r<4;++r){
        pa0[r]   = f2bfh(ex2(s00[r]));
        pa0[4+r] = f2bfh(ex2(s01[r]));
        pa1[r]   = f2bfh(ex2(s10[r]));
        pa1[4+r] = f2bfh(ex2(s11[r]));
      }
      PRIO(1);
      acc[0][0] = mfma16(pa0, g0, acc[0][0]);
      acc[1][0] = mfma16(pa1, g0, acc[1][0]);
      acc[0][1] = mfma16(pa0, g1, acc[0][1]);
      acc[1][1] = mfma16(pa1, g1, acc[1][1]);
      acc[0][2] = mfma16(pa0, g2, acc[0][2]);
      acc[1][2] = mfma16(pa1, g2, acc[1][2]);
      acc[0][3] = mfma16(pa0, g3, acc[0][3]);
      acc[1][3] = mfma16(pa1, g3, acc[1][3]);
      PRIO(0);
    }
    // ---- sub-chunk 1 (m rows 32..63) ----
    {
      const u16* rb0 = bPH + (32 + l15)*64;
      const u16* rb1 = rb0 + 16*64;
      s16x8 ap00 = *(const s16x8*)(rb0 + ((lg     ^ rx)<<3));
      s16x8 ap01 = *(const s16x8*)(rb0 + (((lg+4) ^ rx)<<3));
      s16x8 ap10 = *(const s16x8*)(rb1 + ((lg     ^ rx)<<3));
      s16x8 ap11 = *(const s16x8*)(rb1 + (((lg+4) ^ rx)<<3));
      f32x4 s00={0.f,0.f,0.f,0.f}, s01={0.f,0.f,0.f,0.f};
      f32x4 s10={0.f,0.f,0.f,0.f}, s11={0.f,0.f,0.f,0.f};
      PRIO(1);
      s00 = mfma16(ap00, bt00, s00); s00 = mfma16(ap01, bt01, s00);
      s01 = mfma16(ap10, bt00, s01); s01 = mfma16(ap11, bt01, s01);
      s10 = mfma16(ap00, bt10, s10); s10 = mfma16(ap01, bt11, s10);
      s11 = mfma16(ap10, bt10, s11); s11 = mfma16(ap11, bt11, s11);
      PRIO(0);
      s16x8 pa0, pa1;
      #pragma unroll
      for(int r=0;r<4;++r){
        pa0[r]   = f2bfh(ex2(s00[r]));
        pa0[4+r] = f2bfh(ex2(s01[r]));
        pa1[r]   = f2bfh(ex2(s10[r]));
        pa1[4+r] = f2bfh(ex2(s11[r]));
      }
      PRIO(1);
      acc[0][0] = mfma16(pa0, g4, acc[0][0]);
      acc[1][0] = mfma16(pa1, g4, acc[1][0]);
      acc[0][1] = mfma16(pa0, g5, acc[0][1]);
      acc[1][1] = mfma16(pa1, g5, acc[1][1]);
      acc[0][2] = mfma16(pa0, g6, acc[0][2]);
      acc[1][2] = mfma16(pa1, g6, acc[1][2]);
      acc[0][3] = mfma16(pa0, g7, acc[0][3]);
      acc[1][3] = mfma16(pa1, g7, acc[1][3]);
      PRIO(0);
    }
  }

  u16* outp = OUTPB + ((size_t)(mpart*NB + b)*NTOK)*CCH;
  #pragma unroll
  for(int n2=0;n2<2;++n2)
    #pragma unroll
    for(int ct=0;ct<4;++ct)
      #pragma unroll
      for(int r=0;r<4;++r)
        outp[(size_t)(nbase + n2*16 + lg*4 + r)*CCH + ct*16 + l15] =
            (u16)f2bfh(acc[n2][ct][r]);
}

// ---------------------------------------------------------------------------
// Kernel 5a: reduce bf16 m-partials -> bf16 OUTS. Pure streaming s16x8.
// ---------------------------------------------------------------------------
__global__ __launch_bounds__(256) void reduce_kernel(
    const u16* __restrict__ OUTPB, u16* __restrict__ OUTS, int msplit){
  const int gid = blockIdx.x*256 + threadIdx.x;          // s16x8 index
  const size_t stride8 = (size_t)NB*NTOK*CCH/8;
  const s16x8* src = (const s16x8*)OUTPB;
  float a[8];
  s16x8 u0 = src[gid];
  #pragma unroll
  for(int k=0;k<8;++k) a[k] = bf2f((u16)u0[k]);
  for(int h=1; h<msplit; ++h){
    s16x8 u = src[(size_t)h*stride8 + gid];
    #pragma unroll
    for(int k=0;k<8;++k) a[k] += bf2f((u16)u[k]);
  }
  s16x8 o;
  #pragma unroll
  for(int k=0;k<8;++k) o[k] = f2bfh(a[k]);
  ((s16x8*)OUTS)[gid] = o;
}

// ---------------------------------------------------------------------------
// Kernel 5b: w_mask 1x1 conv + residual. 512 thr = 64 tokens x 8 waves
// (8 output channels each); OUTS read as bf16, unpacked in registers.
// ---------------------------------------------------------------------------
__global__ __launch_bounds__(512, 2) void conv_kernel(
    const u16* __restrict__ OUTS, const float* __restrict__ w_mask,
    const float* __restrict__ x, float* __restrict__ out){
  const int b = blockIdx.y;
  const int nl = threadIdx.x & 63;
  const int n = blockIdx.x*64 + nl;
  const int q = __builtin_amdgcn_readfirstlane((int)(threadIdx.x >> 6)); // 0..7
  const s16x8* vr = (const s16x8*)(OUTS + ((size_t)b*NTOK + n)*CCH);
  float v[64];
  #pragma unroll
  for(int k=0;k<8;++k){
    s16x8 u = vr[k];
    #pragma unroll
    for(int e=0;e<8;++e) v[k*8+e] = bf2f((u16)u[e]);
  }
  const float* wm = w_mask + q*8*32;       // 8 rows of 32, wave-uniform
  #pragma unroll
  for(int jj=0;jj<8;++jj){
    float a0 = 0.f, a1 = 0.f;
    #pragma unroll
    for(int ic=0;ic<32;++ic){
      float w = wm[jj*32 + ic];
      a0 = fmaf(w, v[2*ic],   a0);
      a1 = fmaf(w, v[2*ic+1], a1);
    }
    const size_t idx = ((size_t)b*CCH + q*8 + jj)*HWSZ + n;
    out[idx]        = a0 + x[idx];
    out[idx + NTOK] = a1 + x[idx + NTOK];
  }
}

// ---------------------------------------------------------------------------
extern "C" void kernel_launch(void* const* d_in, const int* in_sizes, int n_in,
                              void* d_out, int out_size, void* d_ws, size_t ws_size,
                              hipStream_t stream){
  const float* x       = (const float*)d_in[0];
  const float* y       = (const float*)d_in[1];
  const float* w_phi   = (const float*)d_in[2];
  const float* w_theta = (const float*)d_in[3];
  const float* w_g     = (const float*)d_in[4];
  const float* w_mask  = (const float*)d_in[5];
  float* out = (float*)d_out;
  char* ws = (char*)d_ws;

  const size_t projB  = (size_t)NB*NTOK*CCH*sizeof(u16);    // 2,359,296
  const size_t fstat  = (size_t)NB*NTOK*sizeof(float);      // 73,728
  const size_t fixed  = 5*projB + (size_t)NSPL*fstat;   // TH,PH,G,G2,OUTS,stats

  int msplit = (ws_size >= fixed + 8*projB) ? 8
             : (ws_size >= fixed + 4*projB) ? 4 : 2;

  size_t off = 0;
  u16*   TH    = (u16*)(ws + off); off += projB;
  u16*   PH    = (u16*)(ws + off); off += projB;
  u16*   G     = (u16*)(ws + off); off += projB;
  u16*   G2    = (u16*)(ws + off); off += projB;
  u16*   OUTPB = (u16*)(ws + off); off += (size_t)msplit*projB;
  u16*   OUTS  = (u16*)(ws + off); off += projB;
  float* CSUMP = (float*)(ws + off); off += (size_t)NSPL*fstat;

  proj_kernel<<<dim3(NTOK/64, NB), 512, 0, stream>>>(x, y, w_phi, w_theta, w_g,
                                                     TH, PH, G);
  passA_kernel<<<dim3((NTOK/128)*NSPL*NB), 256, 0, stream>>>(TH, PH, CSUMP);
  scale_g_kernel<<<dim3(NB*NCHT), 256, 0, stream>>>(G, CSUMP, G2);
  const int gB = (NTOK/128)*msplit*NB;
  switch(msplit){
    case 8:  passB_kernel<8><<<dim3(gB),256,0,stream>>>(TH,PH,G2,OUTPB); break;
    case 4:  passB_kernel<4><<<dim3(gB),256,0,stream>>>(TH,PH,G2,OUTPB); break;
    default: passB_kernel<2><<<dim3(gB),256,0,stream>>>(TH,PH,G2,OUTPB); break;
  }
  reduce_kernel<<<dim3((NB*NTOK*CCH/8)/256), 256, 0, stream>>>(OUTPB, OUTS, msplit);
  conv_kernel<<<dim3(NTOK/64, NB), 512, 0, stream>>>(OUTS, w_mask, x, out);
}